// Round 4
// baseline (67.007 us; speedup 1.0000x reference)
//
#include <hip/hip_runtime.h>
#include <hip/hip_bf16.h>
#include <math.h>

#define B_ 128
#define C_ 8
#define T_ 128
#define K_ 20
#define S_ 128

#define XROW 388            // cc x row stride: %4==0 (float4), %32==4 (groups de-alias)
#define BTROW 132
#define SWZ(j) ((j) ^ ((((j) >> 5) & 7) << 2))
#define XP_GUARD 16         // absorbs SWZ overflow writes from j in [384,388)
#define BT_BASE (4 * XROW + XP_GUARD)   // 1568 floats
#define DTW_TILE 1152       // per-wave: xlo 512 | xhi 512 | X2 128
#define SMEMF 4608          // floats: dtw 4*1152; cc 1568+4*528=3680

__device__ __forceinline__ float dpp_shr1(float v) {
    // v_mov_b32_dpp row_shr:1 — lane i gets lane i-1 within each 16-lane row;
    // lane 0 of each row gets 0 (bound_ctrl), overridden by caller.
    int r = __builtin_amdgcn_update_dpp(0, __float_as_int(v), 0x111, 0xf, 0xf, true);
    return __int_as_float(r);
}

// 1440 blocks x 256 threads. u%9==0 -> DTW (4 waves, each 4 pairs: 16-lane
// groups, 8 DP columns/lane). Else -> CC (4 waves sharing one (b,half) x-tile,
// each wave one k: 4 channels x 16 lanes x 16 lags).
__global__ __launch_bounds__(256) void fused_kernel(const float* __restrict__ x,
                                                    const float* __restrict__ bary,
                                                    const float* __restrict__ top_dist,
                                                    const float* __restrict__ bottom_cc,
                                                    int* __restrict__ dtw_gt,
                                                    int* __restrict__ cc_fail2) {
    __shared__ __align__(16) float smem[SMEMF];
    const float INF = __builtin_inff();
    int u = blockIdx.x;
    int tid = threadIdx.x;
    int w = tid >> 6;
    int lane = tid & 63;

    if (u % 9 == 0) {
        // ------------------------------ DTW ------------------------------
        int pg = (u / 9) * 4 + w;        // pair-group 0..639
        int b  = pg / 5;
        int kg = pg - b * 5;
        int g  = lane >> 4;              // sub-pair in wave
        int gl = lane & 15;
        int ks = kg * 4 + g;             // 0..19
        float* tile = smem + w * DTW_TILE;

        // Stage x[b] -> plane-split (per wave; coalesced float4 loads).
        const float* xb_ = x + (size_t)b * (C_ * T_);
        #pragma unroll
        for (int r = 0; r < 4; ++r) {
            int f = r * 64 + lane;       // float4 index 0..255
            int c = f >> 5;
            int t0 = (f & 31) * 4;
            float4 v = *(const float4*)(xb_ + c * T_ + t0);
            float* dst = tile + (c >> 2) * 512 + (c & 3);
            dst[(t0 + 0) * 4] = v.x;
            dst[(t0 + 1) * 4] = v.y;
            dst[(t0 + 2) * 4] = v.z;
            dst[(t0 + 3) * 4] = v.w;
        }
        __syncthreads();
        // X2[t]
        #pragma unroll
        for (int r = 0; r < 2; ++r) {
            int t = r * 64 + lane;
            float4 xa = *(const float4*)(tile + t * 4);
            float4 xh = *(const float4*)(tile + 512 + t * 4);
            float s = xa.x * xa.x;
            s = fmaf(xa.y, xa.y, s); s = fmaf(xa.z, xa.z, s); s = fmaf(xa.w, xa.w, s);
            s = fmaf(xh.x, xh.x, s); s = fmaf(xh.y, xh.y, s); s = fmaf(xh.z, xh.z, s);
            s = fmaf(xh.w, xh.w, s);
            tile[1024 + t] = s;
        }
        __syncthreads();

        // 8 barycenter columns per lane (contiguous 64 floats): -2*b and B2.
        float bv[8][8], B2s[8];
        {
            const float4* bp = (const float4*)(bary + (size_t)ks * (S_ * C_) + 64 * gl);
            #pragma unroll
            for (int r = 0; r < 8; ++r) {
                float4 q0 = bp[2 * r], q1 = bp[2 * r + 1];
                bv[r][0] = q0.x; bv[r][1] = q0.y; bv[r][2] = q0.z; bv[r][3] = q0.w;
                bv[r][4] = q1.x; bv[r][5] = q1.y; bv[r][6] = q1.z; bv[r][7] = q1.w;
                float s = 0.f;
                #pragma unroll
                for (int ch = 0; ch < 8; ++ch) s = fmaf(bv[r][ch], bv[r][ch], s);
                B2s[r] = s;
                #pragma unroll
                for (int ch = 0; ch < 8; ++ch) bv[r][ch] *= -2.f;
            }
        }

        float cr[8];
        #pragma unroll
        for (int i = 0; i < 8; ++i) cr[i] = INF;
        bool is0 = (gl == 0);
        float lcp = is0 ? 0.f : INF;     // virtual D[-1][-1]=0 for col 0

        const float* tX2 = tile + 1024;
        for (int d = 0; d < T_ + 15; ++d) {
            float lc = dpp_shr1(cr[7]);
            lc = is0 ? INF : lc;
            int t = d - gl;
            int tc = t < 0 ? 0 : (t > T_ - 1 ? T_ - 1 : t);
            // Pre-start lanes: lc=lcp=cr=INF -> n=INF (state preserved).
            // Post-end lanes: garbage rows never feed a live cell.
            float bse = tX2[tc];
            float4 xa = *(const float4*)(tile + tc * 4);
            float4 xh = *(const float4*)(tile + 512 + tc * 4);
            float xv[8];
            xv[0] = xa.x; xv[1] = xa.y; xv[2] = xa.z; xv[3] = xa.w;
            xv[4] = xh.x; xv[5] = xh.y; xv[6] = xh.z; xv[7] = xh.w;
            float a[8];
            #pragma unroll
            for (int r = 0; r < 8; ++r) {
                float ar = bse + B2s[r];
                #pragma unroll
                for (int ch = 0; ch < 8; ++ch) ar = fmaf(bv[r][ch], xv[ch], ar);
                a[r] = fmaxf(ar, 0.f);
            }
            float diag = lcp, left = lc;
            #pragma unroll
            for (int r = 0; r < 8; ++r) {
                float n = a[r] + fminf(fminf(cr[r], diag), left);
                diag = cr[r];
                cr[r] = n;
                left = n;
            }
            lcp = lc;
        }

        if (gl == 15)
            dtw_gt[b * K_ + ks] = (logf(cr[7]) > top_dist[ks]) ? 1 : 0;
    } else {
        // ------------------------------ CC -------------------------------
        int cb = u - u / 9 - 1;          // 0..1279
        int bh = cb / 5;                 // (b, half) 0..255
        int g5 = cb - bh * 5;
        int b  = bh >> 1;
        int h  = bh & 1;
        int kk = g5 * 4 + w;             // 0..19
        int cbase = h * 4;

        float* xp = smem;                        // 4 x XROW (+guard), swizzled
        float* bt = smem + BT_BASE + w * (4 * BTROW);

        // Stage x half cooperatively (shared by the 4 waves).
        const float* xsrc = x + ((size_t)b * C_ + cbase) * T_;
        #pragma unroll
        for (int c = 0; c < 4; ++c) {
            for (int j = tid; j < XROW; j += 256) {
                int t = j - (S_ - 1);
                float v = (t >= 0 && t < T_) ? xsrc[c * T_ + t] : 0.f;
                xp[c * XROW + SWZ(j)] = v;   // overflow for j>=384 lands on zero-slots/guard
            }
        }
        // Stage bt (per wave): coalesced float4 + transposed scatter.
        #pragma unroll
        for (int r = 0; r < 2; ++r) {
            int s = r * 64 + lane;
            float4 q = *(const float4*)(bary + ((size_t)kk * S_ + s) * C_ + cbase);
            bt[0 * BTROW + s] = q.x;
            bt[1 * BTROW + s] = q.y;
            bt[2 * BTROW + s] = q.z;
            bt[3 * BTROW + s] = q.w;
        }
        __syncthreads();

        int cl = lane >> 4;
        int gl = lane & 15;
        int lag0 = gl << 4;              // 16 lags/lane
        const float* xr = xp + cl * XROW;
        const float* br = bt + cl * BTROW;

        float wdw[20];
        #pragma unroll
        for (int i = 0; i < 5; ++i) {
            float4 v = *(const float4*)&xr[SWZ(lag0 + i * 4)];
            wdw[i * 4 + 0] = v.x; wdw[i * 4 + 1] = v.y;
            wdw[i * 4 + 2] = v.z; wdw[i * 4 + 3] = v.w;
        }
        float acc[16];
        #pragma unroll
        for (int j = 0; j < 16; ++j) acc[j] = 0.f;

        #pragma unroll 8
        for (int s4 = 0; s4 < S_; s4 += 4) {
            float4 bq = *(const float4*)&br[s4];
            float bvals[4] = {bq.x, bq.y, bq.z, bq.w};
            #pragma unroll
            for (int uu = 0; uu < 4; ++uu) {
                #pragma unroll
                for (int j = 0; j < 16; ++j)
                    acc[j] = fmaf(wdw[uu + j], bvals[uu], acc[j]);
            }
            #pragma unroll
            for (int i = 0; i < 16; ++i) wdw[i] = wdw[i + 4];
            float4 v = *(const float4*)&xr[SWZ(lag0 + s4 + 20)];  // last iter: unused, in-bounds
            wdw[16] = v.x; wdw[17] = v.y; wdw[18] = v.z; wdw[19] = v.w;
        }

        if (gl == 15) acc[15] = -INF;    // lag 255 doesn't exist
        float m = acc[0];
        #pragma unroll
        for (int j = 1; j < 16; ++j) m = fmaxf(m, acc[j]);
        #pragma unroll
        for (int off = 8; off >= 1; off >>= 1)
            m = fmaxf(m, __shfl_xor(m, off));

        bool fail = false;
        if (gl == 0) fail = (m <= bottom_cc[kk * C_ + cbase + cl]);
        unsigned long long bal = __ballot(fail);
        if (lane == 0) cc_fail2[(b * K_ + kk) * 2 + h] = (bal != 0ULL) ? 1 : 0;
    }
}

__global__ void final_kernel(const int* __restrict__ preds,
                             const int* __restrict__ dtw_gt,
                             const int* __restrict__ cc_fail2,
                             int* __restrict__ out) {
    int b = threadIdx.x;
    if (b < B_) {
        int dtw_all = 1, cc_all = 1;
        #pragma unroll
        for (int k = 0; k < K_; ++k) {
            dtw_all &= dtw_gt[b * K_ + k];
            cc_all &= (cc_fail2[(b * K_ + k) * 2] | cc_fail2[(b * K_ + k) * 2 + 1]);
        }
        out[b] = (dtw_all | cc_all) ? K_ : preds[b];
    }
}

extern "C" void kernel_launch(void* const* d_in, const int* in_sizes, int n_in,
                              void* d_out, int out_size, void* d_ws, size_t ws_size,
                              hipStream_t stream) {
    const float* x         = (const float*)d_in[0];  // [B, C, T]
    const int*   preds     = (const int*)d_in[1];    // [B]
    const float* bary      = (const float*)d_in[2];  // [K, S, C]
    const float* top_dist  = (const float*)d_in[3];  // [K]
    const float* bottom_cc = (const float*)d_in[4];  // [K, C]
    int* out = (int*)d_out;                          // [B] int32

    int* dtw_gt   = (int*)d_ws;                // [B*K]
    int* cc_fail2 = dtw_gt + B_ * K_;          // [B*K*2]

    fused_kernel<<<1440, 256, 0, stream>>>(x, bary, top_dist, bottom_cc, dtw_gt, cc_fail2);
    final_kernel<<<1, 128, 0, stream>>>(preds, dtw_gt, cc_fail2, out);
}